// Round 1
// baseline (13629.456 us; speedup 1.0000x reference)
//
#include <hip/hip_runtime.h>
#include <math.h>

#define NN 10000
#define EE 320000
#define INC 64
#define HH 128
#define G4 512

__device__ __forceinline__ float sigm(float x) { return 1.f / (1.f + __expf(-x)); }
__device__ __forceinline__ float tanh_fast(float x) { return 1.f - 2.f / (1.f + __expf(2.f * x)); }

#define RL(v, l) __uint_as_float(__builtin_amdgcn_readlane(__float_as_uint(v), (l)))

// ---------------- init: zero bn stats (both layers) ----------------
__global__ void k_init(float* stats) {
    int i = blockIdx.x * 256 + threadIdx.x;
    if (i < 512) stats[i] = 0.f;
}

// ---------------- broadcast bias into agg buffer ----------------
__global__ void k_bias_bcast(float* __restrict__ out, const float* __restrict__ b) {
    int i = blockIdx.x * 256 + threadIdx.x;
    if (i < NN * HH) out[i] = b[i & (HH - 1)];
}

// ---------------- C[M,128] = A[M,K] @ B[K,128], K in {64,128} ----------------
__global__ __launch_bounds__(256) void k_gemm_ab(const float* __restrict__ A,
                                                 const float* __restrict__ B,
                                                 float* __restrict__ C,
                                                 int M, int K, int kshift) {
    __shared__ float Alds[32 * 129];
    int tid = threadIdx.x;
    int m0 = blockIdx.x * 32;
    for (int i = tid; i < 32 * K; i += 256) {
        int r = i >> kshift;
        int k = i & (K - 1);
        int m = m0 + r;
        Alds[r * 129 + k] = (m < M) ? A[m * K + k] : 0.f;
    }
    __syncthreads();
    int r = tid >> 3;
    int cg = (tid & 7) * 16;
    float acc[16];
#pragma unroll
    for (int j = 0; j < 16; j++) acc[j] = 0.f;
#pragma unroll 4
    for (int k = 0; k < K; ++k) {
        float a = Alds[r * 129 + k];
        const float4* Brow = (const float4*)(B + k * HH + cg);
        float4 b0 = Brow[0], b1 = Brow[1], b2 = Brow[2], b3 = Brow[3];
        acc[0]  = fmaf(a, b0.x, acc[0]);  acc[1]  = fmaf(a, b0.y, acc[1]);
        acc[2]  = fmaf(a, b0.z, acc[2]);  acc[3]  = fmaf(a, b0.w, acc[3]);
        acc[4]  = fmaf(a, b1.x, acc[4]);  acc[5]  = fmaf(a, b1.y, acc[5]);
        acc[6]  = fmaf(a, b1.z, acc[6]);  acc[7]  = fmaf(a, b1.w, acc[7]);
        acc[8]  = fmaf(a, b2.x, acc[8]);  acc[9]  = fmaf(a, b2.y, acc[9]);
        acc[10] = fmaf(a, b2.z, acc[10]); acc[11] = fmaf(a, b2.w, acc[11]);
        acc[12] = fmaf(a, b3.x, acc[12]); acc[13] = fmaf(a, b3.y, acc[13]);
        acc[14] = fmaf(a, b3.z, acc[14]); acc[15] = fmaf(a, b3.w, acc[15]);
    }
    int m = m0 + r;
    if (m < M) {
        float4* Crow = (float4*)(C + m * HH + cg);
        Crow[0] = make_float4(acc[0], acc[1], acc[2], acc[3]);
        Crow[1] = make_float4(acc[4], acc[5], acc[6], acc[7]);
        Crow[2] = make_float4(acc[8], acc[9], acc[10], acc[11]);
        Crow[3] = make_float4(acc[12], acc[13], acc[14], acc[15]);
    }
}

// ---------------- C[M,512] = A[M,128] @ B[512,128]^T + bias0 + bias1 ----------------
__global__ __launch_bounds__(256) void k_gemm_abt(const float* __restrict__ A,
                                                   const float* __restrict__ B,
                                                   const float* __restrict__ bias0,
                                                   const float* __restrict__ bias1,
                                                   float* __restrict__ C, int M) {
    __shared__ float Alds[32 * 132];
    int tid = threadIdx.x;
    int m0 = blockIdx.x * 32;
    for (int i = tid; i < 32 * 128; i += 256) {
        int r = i >> 7;
        int k = i & 127;
        int m = m0 + r;
        Alds[r * 132 + k] = (m < M) ? A[m * 128 + k] : 0.f;
    }
    __syncthreads();
    int r = tid >> 3;
    int jb = blockIdx.y * 64 + (tid & 7) * 8;
    float acc[8];
#pragma unroll
    for (int j = 0; j < 8; j++) acc[j] = 0.f;
    const float* a_ptr = &Alds[r * 132];
#pragma unroll 8
    for (int k4 = 0; k4 < 32; ++k4) {
        float4 a = *(const float4*)(a_ptr + 4 * k4);
#pragma unroll
        for (int j = 0; j < 8; j++) {
            float4 b = *(const float4*)(B + (jb + j) * 128 + 4 * k4);
            acc[j] = fmaf(a.x, b.x, acc[j]);
            acc[j] = fmaf(a.y, b.y, acc[j]);
            acc[j] = fmaf(a.z, b.z, acc[j]);
            acc[j] = fmaf(a.w, b.w, acc[j]);
        }
    }
    int m = m0 + r;
    if (m < M) {
#pragma unroll
        for (int j = 0; j < 8; j++)
            C[m * 512 + jb + j] = acc[j] + bias0[jb + j] + bias1[jb + j];
    }
}

// ---------------- scatter: agg[dst] += h[src]*ew ----------------
__global__ void k_scatter(const float* __restrict__ h, const int* __restrict__ ei,
                          const float* __restrict__ ew, float* agg) {
    int gid = blockIdx.x * 256 + threadIdx.x;
    if (gid >= EE * 32) return;
    int e = gid >> 5;
    int q = (gid & 31) << 2;
    int src = ei[e];
    int dst = ei[EE + e];
    float w = ew[e];
    float4 v = *(const float4*)(h + src * 128 + q);
    float* p = agg + dst * 128 + q;
    atomicAdd(p + 0, v.x * w);
    atomicAdd(p + 1, v.y * w);
    atomicAdd(p + 2, v.z * w);
    atomicAdd(p + 3, v.w * w);
}

// ---------------- per-feature sum / sumsq ----------------
__global__ __launch_bounds__(256) void k_bn_stats(const float* __restrict__ x,
                                                   float* __restrict__ stats) {
    int c = threadIdx.x & 127;
    int half = threadIdx.x >> 7;
    float s = 0.f, q = 0.f;
    for (int r = blockIdx.x * 2 + half; r < NN; r += gridDim.x * 2) {
        float v = x[r * HH + c];
        s += v;
        q = fmaf(v, v, q);
    }
    __shared__ float ls[256], lq[256];
    ls[threadIdx.x] = s;
    lq[threadIdx.x] = q;
    __syncthreads();
    if (half == 0) {
        atomicAdd(&stats[c], s + ls[128 + c]);
        atomicAdd(&stats[128 + c], q + lq[128 + c]);
    }
}

// ---------------- bn + relu elementwise ----------------
__global__ void k_bn_relu(const float* __restrict__ x, const float* __restrict__ stats,
                          const float* __restrict__ g, const float* __restrict__ be,
                          float* __restrict__ out) {
    int i = blockIdx.x * 256 + threadIdx.x;
    if (i >= NN * HH) return;
    int c = i & 127;
    float mean = stats[c] * (1.f / NN);
    float var = fmaf(-mean, mean, stats[128 + c] * (1.f / NN));
    float alpha = g[c] * rsqrtf(var + 1e-5f);
    float beta = fmaf(-mean, alpha, be[c]);
    out[i] = fmaxf(0.f, fmaf(x[i], alpha, beta));
}

// ---------------- the sequential bidirectional LSTM scan ----------------
__global__ __launch_bounds__(512, 2) void k_lstm(const float* __restrict__ xpf,
                                                  const float* __restrict__ xpb,
                                                  const float* __restrict__ whf,
                                                  const float* __restrict__ whb,
                                                  float* __restrict__ hf,
                                                  float* __restrict__ hb) {
    const int dir = blockIdx.x;
    const float* __restrict__ xp = dir ? xpb : xpf;
    const float* __restrict__ Whh = dir ? whb : whf;
    float* __restrict__ hs = dir ? hb : hf;
    const int j = threadIdx.x;

    // pin this gate's Whh row in VGPRs
    float w[128];
    {
        const float4* wr = (const float4*)(Whh + j * 128);
#pragma unroll
        for (int k4 = 0; k4 < 32; ++k4) {
            float4 v = wr[k4];
            w[4 * k4 + 0] = v.x;
            w[4 * k4 + 1] = v.y;
            w[4 * k4 + 2] = v.z;
            w[4 * k4 + 3] = v.w;
        }
    }

    __shared__ float h_lds[128];
    __shared__ float gate_lds[512];
    if (j < 128) h_lds[j] = 0.f;
    float c = 0.f;
    float hlo = 0.f, hhi = 0.f;
    __syncthreads();

    const int gtype = j >> 7;  // 0:i 1:f 2:g 3:o
    int t0 = dir ? (NN - 1) : 0;
    float xcur = xp[t0 * G4 + j];

    for (int step = 0; step < NN; ++step) {
        int t = dir ? (NN - 1 - step) : step;
        int sn = (step + 1 < NN) ? step + 1 : step;
        int tn = dir ? (NN - 1 - sn) : sn;
        float xnext = xp[tn * G4 + j];  // prefetch, consumed next iter

        float a0 = 0.f, a1 = 0.f, a2 = 0.f, a3 = 0.f;
#pragma unroll
        for (int k = 0; k < 64; k += 4) {
            a0 = fmaf(RL(hlo, k + 0), w[k + 0], a0);
            a1 = fmaf(RL(hlo, k + 1), w[k + 1], a1);
            a2 = fmaf(RL(hlo, k + 2), w[k + 2], a2);
            a3 = fmaf(RL(hlo, k + 3), w[k + 3], a3);
        }
#pragma unroll
        for (int k = 0; k < 64; k += 4) {
            a0 = fmaf(RL(hhi, k + 0), w[64 + k + 0], a0);
            a1 = fmaf(RL(hhi, k + 1), w[64 + k + 1], a1);
            a2 = fmaf(RL(hhi, k + 2), w[64 + k + 2], a2);
            a3 = fmaf(RL(hhi, k + 3), w[64 + k + 3], a3);
        }
        float pre = ((a0 + a1) + (a2 + a3)) + xcur;
        float act = (gtype == 2) ? tanh_fast(pre) : sigm(pre);
        gate_lds[j] = act;
        __syncthreads();

        if (j < 128) {
            float gi = gate_lds[j];
            float gf = gate_lds[128 + j];
            float gg = gate_lds[256 + j];
            float go = gate_lds[384 + j];
            c = fmaf(gf, c, gi * gg);
            float h = go * tanh_fast(c);
            h_lds[j] = h;
            hs[t * HH + j] = h;
        }
        __syncthreads();
        int l = j & 63;
        hlo = h_lds[l];
        hhi = h_lds[64 + l];
        xcur = xnext;
    }
}

// ---------------- out = [hf|hb] @ Wo + bo ----------------
__global__ void k_out(const float* __restrict__ hf, const float* __restrict__ hb,
                      const float* __restrict__ Wo, const float* __restrict__ bo,
                      float* __restrict__ out) {
    int idx = blockIdx.x * 256 + threadIdx.x;
    if (idx >= NN * 12) return;
    int n = idx / 12;
    int p = idx - n * 12;
    float acc = bo[p];
    const float4* hfr = (const float4*)(hf + n * 128);
    const float4* hbr = (const float4*)(hb + n * 128);
#pragma unroll 4
    for (int k4 = 0; k4 < 32; ++k4) {
        float4 v = hfr[k4];
        acc = fmaf(v.x, Wo[(4 * k4 + 0) * 12 + p], acc);
        acc = fmaf(v.y, Wo[(4 * k4 + 1) * 12 + p], acc);
        acc = fmaf(v.z, Wo[(4 * k4 + 2) * 12 + p], acc);
        acc = fmaf(v.w, Wo[(4 * k4 + 3) * 12 + p], acc);
    }
#pragma unroll 4
    for (int k4 = 0; k4 < 32; ++k4) {
        float4 v = hbr[k4];
        acc = fmaf(v.x, Wo[(128 + 4 * k4 + 0) * 12 + p], acc);
        acc = fmaf(v.y, Wo[(128 + 4 * k4 + 1) * 12 + p], acc);
        acc = fmaf(v.z, Wo[(128 + 4 * k4 + 2) * 12 + p], acc);
        acc = fmaf(v.w, Wo[(128 + 4 * k4 + 3) * 12 + p], acc);
    }
    out[idx] = acc;
}

extern "C" void kernel_launch(void* const* d_in, const int* in_sizes, int n_in,
                              void* d_out, int out_size, void* d_ws, size_t ws_size,
                              hipStream_t stream) {
    const float* x    = (const float*)d_in[0];
    const int*   ei   = (const int*)d_in[1];
    const float* ew   = (const float*)d_in[2];
    const float* W1   = (const float*)d_in[3];
    const float* b1   = (const float*)d_in[4];
    const float* g1   = (const float*)d_in[5];
    const float* be1  = (const float*)d_in[6];
    const float* W2   = (const float*)d_in[7];
    const float* b2   = (const float*)d_in[8];
    const float* g2   = (const float*)d_in[9];
    const float* be2  = (const float*)d_in[10];
    const float* Wihf = (const float*)d_in[11];
    const float* Whhf = (const float*)d_in[12];
    const float* bihf = (const float*)d_in[13];
    const float* bhhf = (const float*)d_in[14];
    const float* Wihb = (const float*)d_in[15];
    const float* Whhb = (const float*)d_in[16];
    const float* bihb = (const float*)d_in[17];
    const float* bhhb = (const float*)d_in[18];
    const float* Wo   = (const float*)d_in[21];
    const float* bo   = (const float*)d_in[22];
    float* out = (float*)d_out;
    float* ws  = (float*)d_ws;

    float* bufA  = ws;                 // 1,280,000
    float* bufB  = ws + 1280000;       // 1,280,000
    float* bufC  = ws + 2560000;       // 1,280,000
    float* stats = ws + 3840000;       // 512
    float* Xf    = ws + 3840512;       // 5,120,000
    float* Xb    = ws + 8960512;       // 5,120,000
    float* hfp   = ws + 14080512;      // 1,280,000
    float* hbp   = ws + 15360512;      // 1,280,000

    const int nElem = NN * HH;
    const int gElem = (nElem + 255) / 256;

    k_init<<<2, 256, 0, stream>>>(stats);

    // ---- GCN layer 1 ----
    k_gemm_ab<<<313, 256, 0, stream>>>(x, W1, bufA, NN, 64, 6);
    k_bias_bcast<<<gElem, 256, 0, stream>>>(bufB, b1);
    k_scatter<<<(EE * 32) / 256, 256, 0, stream>>>(bufA, ei, ew, bufB);
    k_bn_stats<<<100, 256, 0, stream>>>(bufB, stats);
    k_bn_relu<<<gElem, 256, 0, stream>>>(bufB, stats, g1, be1, bufC);

    // ---- GCN layer 2 ----
    k_gemm_ab<<<313, 256, 0, stream>>>(bufC, W2, bufA, NN, 128, 7);
    k_bias_bcast<<<gElem, 256, 0, stream>>>(bufB, b2);
    k_scatter<<<(EE * 32) / 256, 256, 0, stream>>>(bufA, ei, ew, bufB);
    k_bn_stats<<<100, 256, 0, stream>>>(bufB, stats + 256);
    k_bn_relu<<<gElem, 256, 0, stream>>>(bufB, stats + 256, g2, be2, bufC);

    // ---- LSTM input projections (batched) ----
    dim3 gx(313, 8);
    k_gemm_abt<<<gx, 256, 0, stream>>>(bufC, Wihf, bihf, bhhf, Xf, NN);
    k_gemm_abt<<<gx, 256, 0, stream>>>(bufC, Wihb, bihb, bhhb, Xb, NN);

    // ---- sequential bidirectional scan (both directions concurrent) ----
    k_lstm<<<2, 512, 0, stream>>>(Xf, Xb, Whhf, Whhb, hfp, hbp);

    // ---- attention is identity (softmax over singleton axis); final matmul ----
    k_out<<<(NN * 12 + 255) / 256, 256, 0, stream>>>(hfp, hbp, Wo, bo, out);
}

// Round 2
// 9004.002 us; speedup vs baseline: 1.5137x; 1.5137x over previous
//
#include <hip/hip_runtime.h>
#include <math.h>

#define NN 10000
#define EE 320000
#define INC 64
#define HH 128
#define G4 512

typedef short short8 __attribute__((ext_vector_type(8)));
typedef float f32x4 __attribute__((ext_vector_type(4)));

__device__ __forceinline__ float sigm(float x) { return 1.f / (1.f + __expf(-x)); }
__device__ __forceinline__ float tanh_fast(float x) { return 1.f - 2.f / (1.f + __expf(2.f * x)); }

// fp32 -> bf16 round-to-nearest-even
__device__ __forceinline__ unsigned short f2bf(float f) {
    unsigned u = __float_as_uint(f);
    unsigned r = u + 0x7FFFu + ((u >> 16) & 1u);
    return (unsigned short)(r >> 16);
}

// ---------------- init: zero bn stats (both layers) ----------------
__global__ void k_init(float* stats) {
    int i = blockIdx.x * 256 + threadIdx.x;
    if (i < 512) stats[i] = 0.f;
}

// ---------------- broadcast bias into agg buffer ----------------
__global__ void k_bias_bcast(float* __restrict__ out, const float* __restrict__ b) {
    int i = blockIdx.x * 256 + threadIdx.x;
    if (i < NN * HH) out[i] = b[i & (HH - 1)];
}

// ---------------- C[M,128] = A[M,K] @ B[K,128], K in {64,128} ----------------
__global__ __launch_bounds__(256) void k_gemm_ab(const float* __restrict__ A,
                                                 const float* __restrict__ B,
                                                 float* __restrict__ C,
                                                 int M, int K, int kshift) {
    __shared__ float Alds[32 * 129];
    int tid = threadIdx.x;
    int m0 = blockIdx.x * 32;
    for (int i = tid; i < 32 * K; i += 256) {
        int r = i >> kshift;
        int k = i & (K - 1);
        int m = m0 + r;
        Alds[r * 129 + k] = (m < M) ? A[m * K + k] : 0.f;
    }
    __syncthreads();
    int r = tid >> 3;
    int cg = (tid & 7) * 16;
    float acc[16];
#pragma unroll
    for (int j = 0; j < 16; j++) acc[j] = 0.f;
#pragma unroll 4
    for (int k = 0; k < K; ++k) {
        float a = Alds[r * 129 + k];
        const float4* Brow = (const float4*)(B + k * HH + cg);
        float4 b0 = Brow[0], b1 = Brow[1], b2 = Brow[2], b3 = Brow[3];
        acc[0]  = fmaf(a, b0.x, acc[0]);  acc[1]  = fmaf(a, b0.y, acc[1]);
        acc[2]  = fmaf(a, b0.z, acc[2]);  acc[3]  = fmaf(a, b0.w, acc[3]);
        acc[4]  = fmaf(a, b1.x, acc[4]);  acc[5]  = fmaf(a, b1.y, acc[5]);
        acc[6]  = fmaf(a, b1.z, acc[6]);  acc[7]  = fmaf(a, b1.w, acc[7]);
        acc[8]  = fmaf(a, b2.x, acc[8]);  acc[9]  = fmaf(a, b2.y, acc[9]);
        acc[10] = fmaf(a, b2.z, acc[10]); acc[11] = fmaf(a, b2.w, acc[11]);
        acc[12] = fmaf(a, b3.x, acc[12]); acc[13] = fmaf(a, b3.y, acc[13]);
        acc[14] = fmaf(a, b3.z, acc[14]); acc[15] = fmaf(a, b3.w, acc[15]);
    }
    int m = m0 + r;
    if (m < M) {
        float4* Crow = (float4*)(C + m * HH + cg);
        Crow[0] = make_float4(acc[0], acc[1], acc[2], acc[3]);
        Crow[1] = make_float4(acc[4], acc[5], acc[6], acc[7]);
        Crow[2] = make_float4(acc[8], acc[9], acc[10], acc[11]);
        Crow[3] = make_float4(acc[12], acc[13], acc[14], acc[15]);
    }
}

// ---------------- C[M,512] = A[M,128] @ B[512,128]^T + bias0 + bias1 ----------------
__global__ __launch_bounds__(256) void k_gemm_abt(const float* __restrict__ A,
                                                   const float* __restrict__ B,
                                                   const float* __restrict__ bias0,
                                                   const float* __restrict__ bias1,
                                                   float* __restrict__ C, int M) {
    __shared__ float Alds[32 * 132];
    int tid = threadIdx.x;
    int m0 = blockIdx.x * 32;
    for (int i = tid; i < 32 * 128; i += 256) {
        int r = i >> 7;
        int k = i & 127;
        int m = m0 + r;
        Alds[r * 132 + k] = (m < M) ? A[m * 128 + k] : 0.f;
    }
    __syncthreads();
    int r = tid >> 3;
    int jb = blockIdx.y * 64 + (tid & 7) * 8;
    float acc[8];
#pragma unroll
    for (int j = 0; j < 8; j++) acc[j] = 0.f;
    const float* a_ptr = &Alds[r * 132];
#pragma unroll 8
    for (int k4 = 0; k4 < 32; ++k4) {
        float4 a = *(const float4*)(a_ptr + 4 * k4);
#pragma unroll
        for (int j = 0; j < 8; j++) {
            float4 b = *(const float4*)(B + (jb + j) * 128 + 4 * k4);
            acc[j] = fmaf(a.x, b.x, acc[j]);
            acc[j] = fmaf(a.y, b.y, acc[j]);
            acc[j] = fmaf(a.z, b.z, acc[j]);
            acc[j] = fmaf(a.w, b.w, acc[j]);
        }
    }
    int m = m0 + r;
    if (m < M) {
#pragma unroll
        for (int j = 0; j < 8; j++)
            C[m * 512 + jb + j] = acc[j] + bias0[jb + j] + bias1[jb + j];
    }
}

// ---------------- scatter: agg[dst] += h[src]*ew ----------------
__global__ void k_scatter(const float* __restrict__ h, const int* __restrict__ ei,
                          const float* __restrict__ ew, float* agg) {
    int gid = blockIdx.x * 256 + threadIdx.x;
    if (gid >= EE * 32) return;
    int e = gid >> 5;
    int q = (gid & 31) << 2;
    int src = ei[e];
    int dst = ei[EE + e];
    float w = ew[e];
    float4 v = *(const float4*)(h + src * 128 + q);
    float* p = agg + dst * 128 + q;
    atomicAdd(p + 0, v.x * w);
    atomicAdd(p + 1, v.y * w);
    atomicAdd(p + 2, v.z * w);
    atomicAdd(p + 3, v.w * w);
}

// ---------------- per-feature sum / sumsq ----------------
__global__ __launch_bounds__(256) void k_bn_stats(const float* __restrict__ x,
                                                   float* __restrict__ stats) {
    int c = threadIdx.x & 127;
    int half = threadIdx.x >> 7;
    float s = 0.f, q = 0.f;
    for (int r = blockIdx.x * 2 + half; r < NN; r += gridDim.x * 2) {
        float v = x[r * HH + c];
        s += v;
        q = fmaf(v, v, q);
    }
    __shared__ float ls[256], lq[256];
    ls[threadIdx.x] = s;
    lq[threadIdx.x] = q;
    __syncthreads();
    if (half == 0) {
        atomicAdd(&stats[c], s + ls[128 + c]);
        atomicAdd(&stats[128 + c], q + lq[128 + c]);
    }
}

// ---------------- bn + relu elementwise ----------------
__global__ void k_bn_relu(const float* __restrict__ x, const float* __restrict__ stats,
                          const float* __restrict__ g, const float* __restrict__ be,
                          float* __restrict__ out) {
    int i = blockIdx.x * 256 + threadIdx.x;
    if (i >= NN * HH) return;
    int c = i & 127;
    float mean = stats[c] * (1.f / NN);
    float var = fmaf(-mean, mean, stats[128 + c] * (1.f / NN));
    float alpha = g[c] * rsqrtf(var + 1e-5f);
    float beta = fmaf(-mean, alpha, be[c]);
    out[i] = fmaxf(0.f, fmaf(x[i], alpha, beta));
}

// ---------------- sequential bidirectional LSTM scan, MFMA recurrent matvec ----------------
// 8 waves. Wave w owns gates [64w, 64w+64) = 4 M-tiles of 16. K=128 = 4 k-tiles of 32.
// A (Whh bf16 fragments) pinned in VGPRs across all 10000 steps.
// B = h broadcast to all 16 MFMA columns (read from LDS as bf16, 16-lane broadcast).
// mfma_f32_16x16x32_bf16 layouts: A lane = 16*(k>>3)+m, elem = k&7; B lane = 16*(k>>3)+n;
// D: col = lane&15, row = 4*(lane>>4)+reg  [HW-verified m89].
__global__ __launch_bounds__(512, 1) void k_lstm(const float* __restrict__ xpf,
                                                  const float* __restrict__ xpb,
                                                  const float* __restrict__ whf,
                                                  const float* __restrict__ whb,
                                                  float* __restrict__ hf,
                                                  float* __restrict__ hb) {
    const int dir = blockIdx.x;
    const float* __restrict__ xp = dir ? xpb : xpf;
    const float* __restrict__ Whh = dir ? whb : whf;
    float* __restrict__ hs = dir ? hb : hf;
    const int j = threadIdx.x;
    const int lane = j & 63;
    const int w = j >> 6;
    const int g16 = lane >> 4;   // k-group within a k-tile
    const int m = lane & 15;     // row within M-tile

    // ---- preload A fragments: Whh rows (gate weights), fp32 -> bf16 RNE, pinned in VGPRs
    short8 af[4][4];
#pragma unroll
    for (int mt = 0; mt < 4; ++mt) {
#pragma unroll
        for (int kt = 0; kt < 4; ++kt) {
            const float* wp = Whh + (64 * w + 16 * mt + m) * 128 + 32 * kt + 8 * g16;
            float4 f0 = *(const float4*)wp;
            float4 f1 = *(const float4*)(wp + 4);
            short8 a;
            a[0] = (short)f2bf(f0.x); a[1] = (short)f2bf(f0.y);
            a[2] = (short)f2bf(f0.z); a[3] = (short)f2bf(f0.w);
            a[4] = (short)f2bf(f1.x); a[5] = (short)f2bf(f1.y);
            a[6] = (short)f2bf(f1.z); a[7] = (short)f2bf(f1.w);
            af[mt][kt] = a;
        }
    }

    __shared__ __align__(16) float gate_lds[512];
    __shared__ __align__(16) short h_bf[128];
    if (j < 128) h_bf[j] = 0;
    float c = 0.f;
    __syncthreads();

    for (int step = 0; step < NN; ++step) {
        int t = dir ? (NN - 1 - step) : step;

        // xproj for this step (only the 128 update threads); issued early so the
        // global-load latency hides under MFMA + barrier + gate-read.
        float x0 = 0.f, x1 = 0.f, x2 = 0.f, x3 = 0.f;
        if (j < 128) {
            const float* xr = xp + t * G4 + j;
            x0 = xr[0]; x1 = xr[128]; x2 = xr[256]; x3 = xr[384];
        }

        // B fragments: h as bf16, broadcast across the 16 N columns.
        short8 bfr[4];
#pragma unroll
        for (int kt = 0; kt < 4; ++kt)
            bfr[kt] = ((const short8*)h_bf)[kt * 4 + g16];

        f32x4 acc[4];
#pragma unroll
        for (int mt = 0; mt < 4; ++mt) acc[mt] = (f32x4){0.f, 0.f, 0.f, 0.f};
#pragma unroll
        for (int kt = 0; kt < 4; ++kt) {
#pragma unroll
            for (int mt = 0; mt < 4; ++mt)
                acc[mt] = __builtin_amdgcn_mfma_f32_16x16x32_bf16(af[mt][kt], bfr[kt], acc[mt], 0, 0, 0);
        }

        // col-0 lanes hold the gate pre-activations (all cols identical); write to LDS
        if (m == 0) {
#pragma unroll
            for (int mt = 0; mt < 4; ++mt)
                *(f32x4*)&gate_lds[64 * w + 16 * mt + 4 * g16] = acc[mt];
        }
        __syncthreads();

        // elementwise LSTM cell update, fp32, one feature per thread (waves 0-1)
        if (j < 128) {
            float gi = gate_lds[j] + x0;
            float gf = gate_lds[128 + j] + x1;
            float gg = gate_lds[256 + j] + x2;
            float go = gate_lds[384 + j] + x3;
            float ig = sigm(gi);
            float fg = sigm(gf);
            float cg = tanh_fast(gg);
            float og = sigm(go);
            c = fmaf(fg, c, ig * cg);
            float h = og * tanh_fast(c);
            hs[t * HH + j] = h;
            h_bf[j] = (short)f2bf(h);
        }
        __syncthreads();
    }
}

// ---------------- out = [hf|hb] @ Wo + bo ----------------
__global__ void k_out(const float* __restrict__ hf, const float* __restrict__ hb,
                      const float* __restrict__ Wo, const float* __restrict__ bo,
                      float* __restrict__ out) {
    int idx = blockIdx.x * 256 + threadIdx.x;
    if (idx >= NN * 12) return;
    int n = idx / 12;
    int p = idx - n * 12;
    float acc = bo[p];
    const float4* hfr = (const float4*)(hf + n * 128);
    const float4* hbr = (const float4*)(hb + n * 128);
#pragma unroll 4
    for (int k4 = 0; k4 < 32; ++k4) {
        float4 v = hfr[k4];
        acc = fmaf(v.x, Wo[(4 * k4 + 0) * 12 + p], acc);
        acc = fmaf(v.y, Wo[(4 * k4 + 1) * 12 + p], acc);
        acc = fmaf(v.z, Wo[(4 * k4 + 2) * 12 + p], acc);
        acc = fmaf(v.w, Wo[(4 * k4 + 3) * 12 + p], acc);
    }
#pragma unroll 4
    for (int k4 = 0; k4 < 32; ++k4) {
        float4 v = hbr[k4];
        acc = fmaf(v.x, Wo[(128 + 4 * k4 + 0) * 12 + p], acc);
        acc = fmaf(v.y, Wo[(128 + 4 * k4 + 1) * 12 + p], acc);
        acc = fmaf(v.z, Wo[(128 + 4 * k4 + 2) * 12 + p], acc);
        acc = fmaf(v.w, Wo[(128 + 4 * k4 + 3) * 12 + p], acc);
    }
    out[idx] = acc;
}

extern "C" void kernel_launch(void* const* d_in, const int* in_sizes, int n_in,
                              void* d_out, int out_size, void* d_ws, size_t ws_size,
                              hipStream_t stream) {
    const float* x    = (const float*)d_in[0];
    const int*   ei   = (const int*)d_in[1];
    const float* ew   = (const float*)d_in[2];
    const float* W1   = (const float*)d_in[3];
    const float* b1   = (const float*)d_in[4];
    const float* g1   = (const float*)d_in[5];
    const float* be1  = (const float*)d_in[6];
    const float* W2   = (const float*)d_in[7];
    const float* b2   = (const float*)d_in[8];
    const float* g2   = (const float*)d_in[9];
    const float* be2  = (const float*)d_in[10];
    const float* Wihf = (const float*)d_in[11];
    const float* Whhf = (const float*)d_in[12];
    const float* bihf = (const float*)d_in[13];
    const float* bhhf = (const float*)d_in[14];
    const float* Wihb = (const float*)d_in[15];
    const float* Whhb = (const float*)d_in[16];
    const float* bihb = (const float*)d_in[17];
    const float* bhhb = (const float*)d_in[18];
    const float* Wo   = (const float*)d_in[21];
    const float* bo   = (const float*)d_in[22];
    float* out = (float*)d_out;
    float* ws  = (float*)d_ws;

    float* bufA  = ws;                 // 1,280,000
    float* bufB  = ws + 1280000;       // 1,280,000
    float* bufC  = ws + 2560000;       // 1,280,000
    float* stats = ws + 3840000;       // 512
    float* Xf    = ws + 3840512;       // 5,120,000
    float* Xb    = ws + 8960512;       // 5,120,000
    float* hfp   = ws + 14080512;      // 1,280,000
    float* hbp   = ws + 15360512;      // 1,280,000

    const int nElem = NN * HH;
    const int gElem = (nElem + 255) / 256;

    k_init<<<2, 256, 0, stream>>>(stats);

    // ---- GCN layer 1 ----
    k_gemm_ab<<<313, 256, 0, stream>>>(x, W1, bufA, NN, 64, 6);
    k_bias_bcast<<<gElem, 256, 0, stream>>>(bufB, b1);
    k_scatter<<<(EE * 32) / 256, 256, 0, stream>>>(bufA, ei, ew, bufB);
    k_bn_stats<<<100, 256, 0, stream>>>(bufB, stats);
    k_bn_relu<<<gElem, 256, 0, stream>>>(bufB, stats, g1, be1, bufC);

    // ---- GCN layer 2 ----
    k_gemm_ab<<<313, 256, 0, stream>>>(bufC, W2, bufA, NN, 128, 7);
    k_bias_bcast<<<gElem, 256, 0, stream>>>(bufB, b2);
    k_scatter<<<(EE * 32) / 256, 256, 0, stream>>>(bufA, ei, ew, bufB);
    k_bn_stats<<<100, 256, 0, stream>>>(bufB, stats + 256);
    k_bn_relu<<<gElem, 256, 0, stream>>>(bufB, stats + 256, g2, be2, bufC);

    // ---- LSTM input projections (batched GEMMs, biases folded in) ----
    dim3 gx(313, 8);
    k_gemm_abt<<<gx, 256, 0, stream>>>(bufC, Wihf, bihf, bhhf, Xf, NN);
    k_gemm_abt<<<gx, 256, 0, stream>>>(bufC, Wihb, bihb, bhhb, Xb, NN);

    // ---- sequential bidirectional scan (both directions concurrent) ----
    k_lstm<<<2, 512, 0, stream>>>(Xf, Xb, Whhf, Whhb, hfp, hbp);

    // ---- attention is identity (softmax over singleton axis); final matmul ----
    k_out<<<(NN * 12 + 255) / 256, 256, 0, stream>>>(hfp, hbp, Wo, bo, out);
}